// Round 17
// baseline (157.157 us; speedup 1.0000x reference)
//
#include <hip/hip_runtime.h>

typedef __bf16 bf16x8 __attribute__((ext_vector_type(8)));
typedef float f32x16 __attribute__((ext_vector_type(16)));
typedef float f32x4 __attribute__((ext_vector_type(4)));

#define S_TOTAL 8192
#define DIM 256
#define BK 16
#define NSP 16

// R17 = R16 + fused ticket fan-in reduction (no second kernel).
// Block = (batch, sp, ih, jh): 128x128 partial tile over kc=512, bf16 MFMA,
// R16's proven staging (2x global_load_lds dwordx4/wave/tile, 512B segments
// both matrices, 3-buf 48KB LDS, depth-2, counted vmcnt(2), 2 blocks/CU,
// XCD mate-swizzle). After writing its bf16 tile to ws, each block:
// __threadfence (release: wbl2) -> atomicAdd(ticket[batch*4+quad]).
// The 16th arriver __threadfence (acquire: inv) and reduces the group's 16
// tiles straight into out (L3-hot reads, overlapped with other groups' tails).
// Tickets (32 ints) live at ws+16MB, zeroed by in-graph hipMemsetAsync.
// Deterministic: fixed summation order; reducer identity irrelevant.
__global__ __launch_bounds__(512, 4) void opm_fused(
    const float* __restrict__ A, const float* __restrict__ Bm,
    __bf16* __restrict__ ws, int* __restrict__ tickets,
    float* __restrict__ out, float* __restrict__ dstf32,
    int nsp, int kc, float scale)
{
    __shared__ float lds[3 * 4096];      // 48 KB: buf b = lds+b*4096 (A 2048 | B 2048)
    __shared__ int lastflag;

    const int tid = threadIdx.x;
    const int w   = tid >> 6;            // 0..7
    const int l   = tid & 63;

    // swizzle: bid = x + 8*(gx*4 + mate); group g = gx*8 + x, 4 mates per g on XCD x
    const int bid  = blockIdx.x;
    const int x    = bid & 7;
    const int r    = bid >> 3;
    const int mate = r & 3;
    const int gx   = r >> 2;
    const int ih   = mate >> 1;
    const int jh   = mate & 1;
    const int g    = gx * 8 + x;
    const int batch = g / nsp;
    const int sp    = g % nsp;

    const long long base = (long long)batch * S_TOTAL * DIM;
    const int s0 = sp * kc;
    const int wr = w >> 2, wc = w & 3;   // 2x4 wave grid
    const int lane31 = l & 31;
    const int hi = l >> 5;
    const int niter = kc / BK;

    f32x16 acc[2] = {};                  // 32 AGPR

    auto issue = [&](int it) {
        float* buf = &lds[(it % 3) * 4096];
        const long long srow = base + (long long)(s0 + it * BK + 2 * w + (l >> 5)) * DIM + 4 * (l & 31);
        __builtin_amdgcn_global_load_lds(
            (const __attribute__((address_space(1))) unsigned int*)(A + srow + ih * 128),
            (__attribute__((address_space(3))) unsigned int*)(buf + 2 * w * 128), 16, 0, 0);
        __builtin_amdgcn_global_load_lds(
            (const __attribute__((address_space(1))) unsigned int*)(Bm + srow + jh * 128),
            (__attribute__((address_space(3))) unsigned int*)(buf + 2048 + 2 * w * 128), 16, 0, 0);
    };

    auto compute = [&](int b3) {
        const float* bufA = &lds[b3 * 4096];
        const float* bufB = bufA + 2048;
        bf16x8 af[2], bfv;
        #pragma unroll
        for (int mi = 0; mi < 2; ++mi)
            #pragma unroll
            for (int e = 0; e < 8; ++e)
                af[mi][e] = (__bf16)bufA[(hi * 8 + e) * 128 + wr * 64 + mi * 32 + lane31];
        #pragma unroll
        for (int e = 0; e < 8; ++e)
            bfv[e] = (__bf16)bufB[(hi * 8 + e) * 128 + wc * 32 + lane31];
        acc[0] = __builtin_amdgcn_mfma_f32_32x32x16_bf16(af[0], bfv, acc[0], 0, 0, 0);
        acc[1] = __builtin_amdgcn_mfma_f32_32x32x16_bf16(af[1], bfv, acc[1], 0, 0, 0);
    };

    issue(0);
    issue(1);

    for (int it = 0; it < niter; ++it) {
        if (it + 1 < niter) asm volatile("s_waitcnt vmcnt(2)" ::: "memory");
        else                asm volatile("s_waitcnt vmcnt(0)" ::: "memory");
        __builtin_amdgcn_s_barrier();
        if (it + 2 < niter) issue(it + 2);
        compute(it % 3);
    }

    if (dstf32) {
        // tiny-ws fallback: f32 direct (nsp==1)
        float* o = dstf32 + (long long)batch * (256 * 256) + (ih * 128) * 256 + jh * 128;
        #pragma unroll
        for (int mi = 0; mi < 2; ++mi)
        #pragma unroll
        for (int q = 0; q < 16; ++q) {
            const int row = (q & 3) + 8 * (q >> 2) + 4 * hi;
            o[(wr * 64 + mi * 32 + row) * 256 + wc * 32 + lane31] = acc[mi][q] * scale;
        }
        return;
    }

    // ---- epilogue: bf16 tile via LDS band-repack -> coalesced stores ----
    __bf16* o = ws + (long long)((batch * nsp + sp) * 4 + ih * 2 + jh) * 16384;
    __bf16* ebuf = (__bf16*)&lds[0];     // 16 KB: 64 rows x 128 cols
    #pragma unroll
    for (int band = 0; band < 2; ++band) {
        __syncthreads();
        if (wr == band) {
            #pragma unroll
            for (int mi = 0; mi < 2; ++mi)
            #pragma unroll
            for (int q = 0; q < 16; ++q) {
                const int lr = mi * 32 + (q & 3) + 8 * (q >> 2) + 4 * hi;
                ebuf[lr * 128 + wc * 32 + lane31] = (__bf16)(acc[mi][q] * scale);
            }
        }
        __syncthreads();
        #pragma unroll
        for (int h = 0; h < 2; ++h) {
            const int G = tid + h * 512;
            *(bf16x8*)&o[band * 8192 + G * 8] = *(const bf16x8*)&ebuf[G * 8];
        }
    }

    // ---- ticket fan-in ----
    __threadfence();                                   // release: tile visible device-wide
    if (tid == 0) {
        const int grp = batch * 4 + ih * 2 + jh;
        lastflag = (atomicAdd(&tickets[grp], 1) == nsp - 1) ? 1 : 0;
    }
    __syncthreads();
    if (!lastflag) return;

    __threadfence();                                   // acquire: see all 16 tiles
    const bf16x8* wsv = (const bf16x8*)ws;
    const long long tbase = ((long long)(batch * nsp) * 4 + ih * 2 + jh) * 2048;
    float* ob = out + (long long)batch * 65536 + (ih * 128) * 256 + jh * 128;

    #pragma unroll 1
    for (int h = 0; h < 4; ++h) {
        const int gg = h * 512 + tid;                  // 0..2047 (bf16x8 group in tile)
        const int rr = gg >> 4;                        // row 0..127
        const int cc = gg & 15;                        // col group
        float sacc[8] = {0.f, 0.f, 0.f, 0.f, 0.f, 0.f, 0.f, 0.f};
        #pragma unroll 1
        for (int half = 0; half < 2; ++half) {
            bf16x8 v[8];
            #pragma unroll
            for (int s8 = 0; s8 < 8; ++s8)
                v[s8] = wsv[tbase + (long long)(half * 8 + s8) * 8192 + gg];
            #pragma unroll
            for (int s8 = 0; s8 < 8; ++s8)
                #pragma unroll
                for (int e = 0; e < 8; ++e) sacc[e] += (float)v[s8][e];
        }
        f32x4 lo  = { sacc[0], sacc[1], sacc[2], sacc[3] };
        f32x4 hi4 = { sacc[4], sacc[5], sacc[6], sacc[7] };
        lo  *= (1.0f / 8192.0f);
        hi4 *= (1.0f / 8192.0f);
        *(f32x4*)&ob[rr * 256 + cc * 8]     = lo;
        *(f32x4*)&ob[rr * 256 + cc * 8 + 4] = hi4;
    }
}

extern "C" void kernel_launch(void* const* d_in, const int* in_sizes, int n_in,
                              void* d_out, int out_size, void* d_ws, size_t ws_size,
                              hipStream_t stream)
{
    (void)in_sizes; (void)n_in; (void)out_size;
    const float* A  = (const float*)d_in[0];
    const float* Bm = (const float*)d_in[1];
    float* out = (float*)d_out;

    const size_t tiles_bytes = (size_t)8 * NSP * 4 * 16384 * sizeof(__bf16);  // 16 MB
    if (ws_size >= tiles_bytes + 32 * sizeof(int)) {
        int* tickets = (int*)((char*)d_ws + tiles_bytes);
        hipMemsetAsync(tickets, 0, 32 * sizeof(int), stream);
        opm_fused<<<8 * NSP * 4, 512, 0, stream>>>(A, Bm, (__bf16*)d_ws, tickets,
                                                   out, nullptr,
                                                   NSP, S_TOTAL / NSP, 1.0f);
    } else {
        // tiny-ws fallback: 32 blocks (8 batch x 4 mates), full K, f32 direct
        opm_fused<<<32, 512, 0, stream>>>(A, Bm, nullptr, nullptr,
                                          out, out, 1, S_TOTAL, 1.0f / 8192.0f);
    }
}

// Round 18
// 34.101 us; speedup vs baseline: 4.6085x; 4.6085x over previous
//
#include <hip/hip_runtime.h>

typedef __bf16 bf16x8 __attribute__((ext_vector_type(8)));
typedef float f32x16 __attribute__((ext_vector_type(16)));
typedef float f32x4 __attribute__((ext_vector_type(4)));

#define S_TOTAL 8192
#define DIM 256
#define BK 16
#define NSP 16

// R18 = R16 (34.0us best) with 4-buf depth-3 pipeline (only change).
// Block = (batch, sp, ih, jh): 128x128 partial tile over kc=512. 512 thr =
// 8 waves (2x4; wave tile 64x32, 32 AGPR). Staging: 2x global_load_lds
// dwordx4/wave/tile (512B segments both matrices), 4-buf 16KB bufs (64KB LDS,
// 2 blocks/CU), depth-3 prefetch, counted vmcnt(4), XCD mate-swizzle
// (dedup FETCH-verified R11/R13/R15/R16). ws = 16 MB bf16.
__global__ __launch_bounds__(512, 4) void opm_partial(
    const float* __restrict__ A, const float* __restrict__ Bm,
    __bf16* __restrict__ dstbf, float* __restrict__ dstf32,
    int nsp, int kc, float scale)
{
    __shared__ float lds[4 * 4096];      // 64 KB: buf b = lds+b*4096 (A 2048 | B 2048)

    const int tid = threadIdx.x;
    const int w   = tid >> 6;            // 0..7
    const int l   = tid & 63;

    // swizzle: bid = x + 8*(gx*4 + mate); group g = gx*8 + x, 4 mates per g on XCD x
    const int bid  = blockIdx.x;
    const int x    = bid & 7;
    const int r    = bid >> 3;
    const int mate = r & 3;
    const int gx   = r >> 2;
    const int ih   = mate >> 1;
    const int jh   = mate & 1;
    const int g    = gx * 8 + x;
    const int batch = g / nsp;
    const int sp    = g % nsp;

    const long long base = (long long)batch * S_TOTAL * DIM;
    const int s0 = sp * kc;
    const int wr = w >> 2, wc = w & 3;   // 2x4 wave grid
    const int lane31 = l & 31;
    const int hi = l >> 5;
    const int niter = kc / BK;           // 32 (split path)

    f32x16 acc[2] = {};                  // 32 AGPR

    auto issue = [&](int it) {
        float* buf = &lds[(it & 3) * 4096];
        const long long srow = base + (long long)(s0 + it * BK + 2 * w + (l >> 5)) * DIM + 4 * (l & 31);
        __builtin_amdgcn_global_load_lds(
            (const __attribute__((address_space(1))) unsigned int*)(A + srow + ih * 128),
            (__attribute__((address_space(3))) unsigned int*)(buf + 2 * w * 128), 16, 0, 0);
        __builtin_amdgcn_global_load_lds(
            (const __attribute__((address_space(1))) unsigned int*)(Bm + srow + jh * 128),
            (__attribute__((address_space(3))) unsigned int*)(buf + 2048 + 2 * w * 128), 16, 0, 0);
    };

    auto compute = [&](int b4) {
        const float* bufA = &lds[b4 * 4096];
        const float* bufB = bufA + 2048;
        bf16x8 af[2], bfv;
        #pragma unroll
        for (int mi = 0; mi < 2; ++mi)
            #pragma unroll
            for (int e = 0; e < 8; ++e)
                af[mi][e] = (__bf16)bufA[(hi * 8 + e) * 128 + wr * 64 + mi * 32 + lane31];
        #pragma unroll
        for (int e = 0; e < 8; ++e)
            bfv[e] = (__bf16)bufB[(hi * 8 + e) * 128 + wc * 32 + lane31];
        acc[0] = __builtin_amdgcn_mfma_f32_32x32x16_bf16(af[0], bfv, acc[0], 0, 0, 0);
        acc[1] = __builtin_amdgcn_mfma_f32_32x32x16_bf16(af[1], bfv, acc[1], 0, 0, 0);
    };

    // prologue: T0..T2 in flight (6 VMEM instrs outstanding)
    issue(0);
    issue(1);
    issue(2);

    for (int it = 0; it < niter; ++it) {
        const int rem = niter - 1 - it;          // tiles outstanding beyond T_it
        if (rem >= 2)      asm volatile("s_waitcnt vmcnt(4)" ::: "memory");
        else if (rem == 1) asm volatile("s_waitcnt vmcnt(2)" ::: "memory");
        else               asm volatile("s_waitcnt vmcnt(0)" ::: "memory");
        __builtin_amdgcn_s_barrier();            // T_it landed; all waves past compute(it-1)
        if (it + 3 < niter) issue(it + 3);       // buf (it+3)&3 == (it-1)&3: consumed
        compute(it & 3);
    }

    // ---- epilogue: 128x128 tile ----
    if (dstf32) {
        float* o = dstf32 + (long long)batch * (256 * 256) + (ih * 128) * 256 + jh * 128;
        #pragma unroll
        for (int mi = 0; mi < 2; ++mi)
        #pragma unroll
        for (int q = 0; q < 16; ++q) {
            const int row = (q & 3) + 8 * (q >> 2) + 4 * hi;
            o[(wr * 64 + mi * 32 + row) * 256 + wc * 32 + lane31] = acc[mi][q] * scale;
        }
    } else {
        // band-repack (2 bands of 64 rows) through dead LDS -> coalesced bf16x8
        __bf16* o = dstbf + (long long)((batch * nsp + sp) * 4 + ih * 2 + jh) * 16384;
        __bf16* ebuf = (__bf16*)&lds[0];     // 16 KB: 64 rows x 128 cols
        #pragma unroll
        for (int band = 0; band < 2; ++band) {
            __syncthreads();
            if (wr == band) {
                #pragma unroll
                for (int mi = 0; mi < 2; ++mi)
                #pragma unroll
                for (int q = 0; q < 16; ++q) {
                    const int lr = mi * 32 + (q & 3) + 8 * (q >> 2) + 4 * hi;
                    ebuf[lr * 128 + wc * 32 + lane31] = (__bf16)(acc[mi][q] * scale);
                }
            }
            __syncthreads();
            #pragma unroll
            for (int h = 0; h < 2; ++h) {
                const int G = tid + h * 512;     // 1024 bf16x8 groups per band
                *(bf16x8*)&o[band * 8192 + G * 8] = *(const bf16x8*)&ebuf[G * 8];
            }
        }
    }
}

// Sum NSP=16 bf16 partials, scale by 1/8192. Fully unrolled (R10-proven).
// ws tile t = ((batch*NSP+sp)*4 + ih*2 + jh): contiguous [128][128] bf16.
__global__ __launch_bounds__(256) void opm_reduce16(
    const __bf16* __restrict__ ws, float* __restrict__ out)
{
    const int idx = blockIdx.x * 256 + threadIdx.x;  // 65536 output bf16x8-groups
    const int batch = idx >> 13;
    const int gg  = idx & 8191;
    const int i   = gg >> 5;                         // 0..255
    const int jg  = gg & 31;                         // col-group (8 wide)
    const int ih  = i >> 7, ir = i & 127;
    const int jh  = jg >> 4, jc = jg & 15;

    const bf16x8* p = (const bf16x8*)ws
        + ((long long)(batch * NSP) * 4 + ih * 2 + jh) * 2048 + ir * 16 + jc;
    bf16x8 v[NSP];
    #pragma unroll
    for (int sp = 0; sp < NSP; ++sp) v[sp] = p[sp * 8192];

    float sacc[8] = {0.f, 0.f, 0.f, 0.f, 0.f, 0.f, 0.f, 0.f};
    #pragma unroll
    for (int sp = 0; sp < NSP; ++sp)
        #pragma unroll
        for (int e = 0; e < 8; ++e) sacc[e] += (float)v[sp][e];

    f32x4 lo = { sacc[0], sacc[1], sacc[2], sacc[3] };
    f32x4 hiv = { sacc[4], sacc[5], sacc[6], sacc[7] };
    lo  *= (1.0f / 8192.0f);
    hiv *= (1.0f / 8192.0f);
    ((f32x4*)out)[idx * 2]     = lo;
    ((f32x4*)out)[idx * 2 + 1] = hiv;
}

extern "C" void kernel_launch(void* const* d_in, const int* in_sizes, int n_in,
                              void* d_out, int out_size, void* d_ws, size_t ws_size,
                              hipStream_t stream)
{
    (void)in_sizes; (void)n_in; (void)out_size;
    const float* A  = (const float*)d_in[0];
    const float* Bm = (const float*)d_in[1];
    float* out = (float*)d_out;

    if (ws_size >= (size_t)8 * NSP * 4 * 16384 * sizeof(__bf16)) {   // 16 MB
        opm_partial<<<8 * NSP * 4, 512, 0, stream>>>(A, Bm, (__bf16*)d_ws, nullptr,
                                                     NSP, S_TOTAL / NSP, 1.0f);
        opm_reduce16<<<256, 256, 0, stream>>>((const __bf16*)d_ws, out);
    } else {
        // tiny-ws fallback: 32 blocks (8 batch x 4 mates), full K, f32 direct
        opm_partial<<<32, 512, 0, stream>>>(A, Bm, nullptr, out, 1, S_TOTAL, 1.0f / 8192.0f);
    }
}